// Round 1
// baseline (179.772 us; speedup 1.0000x reference)
//
#include <hip/hip_runtime.h>
#include <hip/hip_bf16.h>

// B=4, S=4096, E=256, NC=16, fp32 in/out. 4 launches:
//  pack_xw:  x (16MB fp32) + wq/wk/wv -> bf16 once (xb/wb live in Opart region,
//            which is dead until flash writes it). Removes ALL fp32->bf16 VALU
//            packing from qkv's hot loop and cuts x HBM reads 48MB->8MB.
//  qkv_gemm: global_load_lds(16B) staging of pre-packed bf16 (dbuf, ONE barrier
//            per K-step), XOR-swizzled LDS units so fragment ds_read_b128 are
//            2-way (was 8-way) bank conflicts. Epilogues unchanged (Q *1/16,
//            K block-swizzled rows, V chunk slabs with key-interleave perm).
//  flash:    Q-tile 128 (u=2), 2 blocks/CU, K dbuf + V dbuf + ps sbuf (74 KB),
//            ONE barrier/chunk, one-behind PV. ps row stride padded 16->20
//            dwords: af reads were 8-way bank-conflicted (2 reads/chunk/wave on
//            the PV critical path), ps writes 4-way -> both now 2-way (free).
//            s_setprio(1) around MFMA clusters (2 independent blocks/SIMD at
//            different phases -> scheduler has roles to arbitrate, T5).
//  proj:     MFMA output projection + slice merge + normalize (dbuf staging)

#define S_ 4096
#define E_ 256
#define B_ 4
#define NC_ 16
#define BS_ (B_ * S_)
#define NS_ 4

typedef __attribute__((ext_vector_type(8))) short bf16x8;
typedef __attribute__((ext_vector_type(4))) float f32x4;

__device__ __forceinline__ unsigned short bf16_rtne(float f) {
    unsigned int u = __float_as_uint(f);
    return (unsigned short)((u + 0x7FFFu + ((u >> 16) & 1u)) >> 16);
}
__device__ __forceinline__ bf16x8 pack8(f32x4 a, f32x4 b) {
    bf16x8 r;
#pragma unroll
    for (int i = 0; i < 4; i++) r[i] = (short)bf16_rtne(a[i]);
#pragma unroll
    for (int i = 0; i < 4; i++) r[4 + i] = (short)bf16_rtne(b[i]);
    return r;
}
__device__ __forceinline__ void gl_lds16(const void* g, void* lds) {
    __builtin_amdgcn_global_load_lds(
        (const __attribute__((address_space(1))) unsigned int*)g,
        (__attribute__((address_space(3))) unsigned int*)lds, 16, 0, 0);
}
// XOR swizzle on 16B LDS units: involution (mask from bits >=3 flips bits 0-2).
__device__ __forceinline__ int swz_u(int q) { return q ^ ((q >> 3) & 7); }

// ---------------------------------------------------------------------------
// pack_xw: x[BS,E] fp32 -> xb bf16 ; wq/wk/wv [E,E] fp32 -> wb bf16 (3 slabs).
// Grid 2144 x 256: units of 8 floats. Pure streaming, bit-identical rtne.
// ---------------------------------------------------------------------------
#define XUNITS_ (BS_ * E_ / 8)     // 524288
#define WUNITS_ (3 * E_ * E_ / 8)  // 24576
__global__ __launch_bounds__(256) void pack_xw(
    const float* __restrict__ x, const float* __restrict__ wq,
    const float* __restrict__ wk, const float* __restrict__ wv,
    short* __restrict__ xb, short* __restrict__ wb) {
    int u = blockIdx.x * 256 + threadIdx.x;
    const float* src;
    short* dst;
    if (u < XUNITS_) {
        src = x + (size_t)u * 8;
        dst = xb + (size_t)u * 8;
    } else {
        int u2 = u - XUNITS_;  // < WUNITS_ by grid construction
        int sel = u2 >> 13;    // 8192 units per weight matrix
        int off = (u2 & 8191) * 8;
        src = ((sel == 0) ? wq : (sel == 1) ? wk : wv) + off;
        dst = wb + sel * (E_ * E_) + off;
    }
    f32x4 a = *(const f32x4*)src;
    f32x4 b = *(const f32x4*)(src + 4);
    *(bf16x8*)dst = pack8(a, b);
}

// ---------------------------------------------------------------------------
// qkv_gemm. Grid (3 sel, BS_/64). 256 thr = 4 waves; wave: 16 rows x 256 cols.
// Staging: global_load_lds 16B of pre-packed bf16, double-buffered, one
// barrier per K-step. LDS unit u holds logical unit swz_u(u) (row-chunk),
// making fragment reads 2-way bank conflicts. Fragment offset collapses to
// a per-thread constant fo = (idx*4+quad) ^ (idx>>1).
// ---------------------------------------------------------------------------
__global__ __launch_bounds__(256) void qkv_gemm(
    const short* __restrict__ xb, const short* __restrict__ wb,
    const float* __restrict__ bq, const float* __restrict__ bk,
    const float* __restrict__ bv, short* __restrict__ Qb,
    short* __restrict__ Kb, short* __restrict__ Vtc) {
    __shared__ __align__(16) short stg[2][10240]; // 2 x 20KB: xt 256u | wt 1024u
    __shared__ __align__(16) short epi[16896];    // 64x264 (Q/K) or 2x8192 (V)

    int t = threadIdx.x;
    int sel = blockIdx.x, m0 = blockIdx.y * 64;
    int lane = t & 63, wid = t >> 6, quad = lane >> 4, idx = lane & 15;

    const short* wsel = wb + sel * (E_ * E_);
    const float* bias = (sel == 0) ? bq : (sel == 1) ? bk : bv;

    // staging sources (swizzled so LDS physical unit q holds logical swz_u(q))
    int ux = swz_u(t);
    const short* xsrc = xb + (size_t)(m0 + (ux >> 2)) * E_ + (ux & 3) * 8;
    const short* wsrc[4];
#pragma unroll
    for (int i = 0; i < 4; i++) {
        int q = i * 256 + t, u = swz_u(q);
        wsrc[i] = wsel + (size_t)(u >> 2) * E_ + (u & 3) * 8;
    }

    // prologue: stage kc=0 into buf 0
    gl_lds16(xsrc, &stg[0][t * 8]);
#pragma unroll
    for (int i = 0; i < 4; i++) gl_lds16(wsrc[i], &stg[0][(256 + i * 256 + t) * 8]);

    f32x4 zf = {0.f, 0.f, 0.f, 0.f};
    f32x4 acc[16];
#pragma unroll
    for (int i = 0; i < 16; i++) acc[i] = zf;

    int fo = (idx * 4 + quad) ^ (idx >> 1); // swizzled fragment unit offset

    for (int it = 0; it < 8; it++) {
        __syncthreads(); // drains DMAs staged one full K-step ago
        if (it < 7) {
            int kc = (it + 1) * 32;
            short* d = stg[(it + 1) & 1];
            gl_lds16(xsrc + kc, &d[t * 8]);
#pragma unroll
            for (int i = 0; i < 4; i++)
                gl_lds16(wsrc[i] + kc, &d[(256 + i * 256 + t) * 8]);
        }
        const short* cb = stg[it & 1];
        bf16x8 af = *(const bf16x8*)&cb[(wid * 64 + fo) * 8];
        const short* cw = &cb[(256 + fo) * 8];
        __builtin_amdgcn_s_setprio(1);
#pragma unroll
        for (int ct = 0; ct < 16; ct++)
            acc[ct] = __builtin_amdgcn_mfma_f32_16x16x32_bf16(
                af, *(const bf16x8*)&cw[ct * 512], acc[ct], 0, 0, 0);
        __builtin_amdgcn_s_setprio(0);
    }

    int qr = quad * 4;
    if (sel == 2) {
        // V: chunk slab, position = key-interleave permutation + 16B swizzle
#pragma unroll
        for (int ct = 0; ct < 16; ct++) {
            int e = ct * 16 + idx;
            float bb = bias[e];
#pragma unroll
            for (int r = 0; r < 4; r++) {
                int mr = wid * 16 + qr + r; // 0..63
                int ckg = mr >> 5, sin = mr & 31;
                int sp = ((sin & 15) << 1) | (sin >> 4); // interleaved position
                int pos = (sp >> 3) ^ ((e >> 1) & 3);
                epi[ckg * 8192 + e * 32 + pos * 8 + (sp & 7)] =
                    (short)bf16_rtne(acc[ct][r] + bb);
            }
        }
        __syncthreads();
        size_t base = ((size_t)((m0 >> 12) * 128 + ((m0 & (S_ - 1)) >> 5))) * 8192;
#pragma unroll
        for (int j = 0; j < 8; j++) {
            int unit = j * 256 + t;
            *(bf16x8*)(Vtc + base + (size_t)unit * 8) = *(const bf16x8*)&epi[unit * 8];
        }
    } else {
        float alpha = (sel == 0) ? 0.0625f : 1.0f;
#pragma unroll
        for (int ct = 0; ct < 16; ct++) {
            int n = ct * 16 + idx;
            float bb = bias[n];
#pragma unroll
            for (int r = 0; r < 4; r++) {
                int row = wid * 16 + qr + r;
                int col = (sel == 1) ? ((((n >> 3) ^ (row & 7)) << 3) | (n & 7)) : n;
                epi[row * 264 + col] = (short)bf16_rtne((acc[ct][r] + bb) * alpha);
            }
        }
        __syncthreads();
        short* out = (sel == 0) ? Qb : Kb;
#pragma unroll
        for (int j = 0; j < 8; j++) {
            int g = j * 256 + t;
            int row = g >> 5, seg = g & 31;
            *(bf16x8*)(out + (size_t)(m0 + row) * E_ + seg * 8) =
                *(const bf16x8*)&epi[row * 264 + seg * 8];
        }
    }
}

// ---------------------------------------------------------------------------
// Flash. Grid (S/128, NS, B). 256 thr = 4 waves; wave owns 2 q-subtiles of 16.
// LDS 74 KB: K dbuf 2x16K | V dbuf 2x16K | ps 10K (row stride padded 16->20
// dwords: af b128 reads and ps b32 writes both 2-way bank conflicts now).
// One barrier per chunk; one-behind PV; staging DMAs get a full chunk of
// flight. setprio(1) around QK / PV MFMA clusters.
// ---------------------------------------------------------------------------
__global__ __launch_bounds__(256, 2) void flash_attn(
    const short* __restrict__ Qb, const short* __restrict__ Kb,
    const short* __restrict__ Vtc, short* __restrict__ Opart,
    float* __restrict__ lpart) {
    __shared__ __align__(16) short lds[37888]; // 75776 B
    // kb(par) = lds + par*8192 ; vb(par) = lds + 16384 + par*8192 ; ps at 32768

    int t = threadIdx.x;
    int b = blockIdx.z, slice = blockIdx.y, q0 = blockIdx.x * 128;
    int key0 = slice * (S_ / NS_);
    const int nchunk = (S_ / NS_) / 32; // 32
    int lane = t & 63, wv = t >> 6, quad = lane >> 4, idx = lane & 15;

    bf16x8 qf[2][8];
#pragma unroll
    for (int u = 0; u < 2; u++) {
        const short* qrow = Qb + (size_t)(b * S_ + q0 + u * 64 + wv * 16 + idx) * E_ + quad * 8;
#pragma unroll
        for (int c = 0; c < 8; c++) qf[u][c] = *(const bf16x8*)(qrow + c * 32);
    }

    f32x4 zf = {0.f, 0.f, 0.f, 0.f};
    f32x4 oacc[2][16];
#pragma unroll
    for (int u = 0; u < 2; u++)
#pragma unroll
        for (int i = 0; i < 16; i++) oacc[u][i] = zf;
    float ls[2][4] = {{0, 0, 0, 0}, {0, 0, 0, 0}};

    const short* kg = Kb + (size_t)(b * S_ + key0) * E_ + lane * 8;
    const short* vg = Vtc + ((size_t)(b * 128 + (key0 >> 5))) * 8192 + lane * 8;
    short* psw = lds + 32768 + wv * 1280; // per-wave 1280 shorts (2u x 16r x 20dw)
    unsigned int* pswu = (unsigned int*)psw;
    int vsw = (quad ^ ((idx >> 1) & 3)) << 3;

    // prologue: stage K(0), V(0), K(1)
#pragma unroll
    for (int j = 0; j < 4; j++) gl_lds16(kg + (wv * 4 + j) * 512, &lds[(wv * 4 + j) * 512]);
#pragma unroll
    for (int j = 0; j < 4; j++) gl_lds16(vg + (wv * 4 + j) * 512, &lds[16384 + (wv * 4 + j) * 512]);
#pragma unroll
    for (int j = 0; j < 4; j++) gl_lds16(kg + 8192 + (wv * 4 + j) * 512, &lds[8192 + (wv * 4 + j) * 512]);
    __syncthreads();

    // QK(0) + exp(0)
    {
        f32x4 s[4] = {zf, zf, zf, zf};
        __builtin_amdgcn_s_setprio(1);
#pragma unroll
        for (int c = 0; c < 8; c++) {
            int p = (((c * 4 + quad) ^ (idx & 7)) << 3);
            bf16x8 k0 = *(const bf16x8*)&lds[idx * 256 + p];
            bf16x8 k1 = *(const bf16x8*)&lds[(16 + idx) * 256 + p];
            s[0] = __builtin_amdgcn_mfma_f32_16x16x32_bf16(qf[0][c], k0, s[0], 0, 0, 0);
            s[1] = __builtin_amdgcn_mfma_f32_16x16x32_bf16(qf[0][c], k1, s[1], 0, 0, 0);
            s[2] = __builtin_amdgcn_mfma_f32_16x16x32_bf16(qf[1][c], k0, s[2], 0, 0, 0);
            s[3] = __builtin_amdgcn_mfma_f32_16x16x32_bf16(qf[1][c], k1, s[3], 0, 0, 0);
        }
        __builtin_amdgcn_s_setprio(0);
#pragma unroll
        for (int u = 0; u < 2; u++)
#pragma unroll
            for (int r = 0; r < 4; r++) {
                float p0 = __expf(s[u * 2][r]);
                float p1 = __expf(s[u * 2 + 1][r]);
                ls[u][r] += p0 + p1;
                pswu[u * 320 + (quad * 4 + r) * 20 + idx] =
                    (unsigned int)bf16_rtne(p0) | ((unsigned int)bf16_rtne(p1) << 16);
            }
    }

    for (int ck = 0; ck < nchunk - 1; ck++) {
        __syncthreads(); // drains K(ck+1), V(ck) DMAs (staged one full chunk ago)
        if (ck + 2 < nchunk) {
            const short* ks = kg + (size_t)(ck + 2) * 8192;
            short* kd = lds + (ck & 1) * 8192;
#pragma unroll
            for (int j = 0; j < 4; j++) gl_lds16(ks + (wv * 4 + j) * 512, &kd[(wv * 4 + j) * 512]);
        }
        {
            const short* vs = vg + (size_t)(ck + 1) * 8192;
            short* vd = lds + 16384 + ((ck + 1) & 1) * 8192;
#pragma unroll
            for (int j = 0; j < 4; j++) gl_lds16(vs + (wv * 4 + j) * 512, &vd[(wv * 4 + j) * 512]);
        }
        // ---- QK(ck+1) ----
        const short* kc = lds + ((ck + 1) & 1) * 8192;
        f32x4 s[4] = {zf, zf, zf, zf};
        __builtin_amdgcn_s_setprio(1);
#pragma unroll
        for (int c = 0; c < 8; c++) {
            int p = (((c * 4 + quad) ^ (idx & 7)) << 3);
            bf16x8 k0 = *(const bf16x8*)&kc[idx * 256 + p];
            bf16x8 k1 = *(const bf16x8*)&kc[(16 + idx) * 256 + p];
            s[0] = __builtin_amdgcn_mfma_f32_16x16x32_bf16(qf[0][c], k0, s[0], 0, 0, 0);
            s[1] = __builtin_amdgcn_mfma_f32_16x16x32_bf16(qf[0][c], k1, s[1], 0, 0, 0);
            s[2] = __builtin_amdgcn_mfma_f32_16x16x32_bf16(qf[1][c], k0, s[2], 0, 0, 0);
            s[3] = __builtin_amdgcn_mfma_f32_16x16x32_bf16(qf[1][c], k1, s[3], 0, 0, 0);
        }
        __builtin_amdgcn_s_setprio(0);
        // ---- af(ck) read (before exp overwrites ps; per-wave DS is in-order)
        bf16x8 af0 = *(const bf16x8*)&psw[idx * 40 + quad * 8];
        bf16x8 af1 = *(const bf16x8*)&psw[640 + idx * 40 + quad * 8];
        // ---- exp(ck+1) -> ps (independent of PV(ck); hides under it) ----
#pragma unroll
        for (int u = 0; u < 2; u++)
#pragma unroll
            for (int r = 0; r < 4; r++) {
                float p0 = __expf(s[u * 2][r]);
                float p1 = __expf(s[u * 2 + 1][r]);
                ls[u][r] += p0 + p1;
                pswu[u * 320 + (quad * 4 + r) * 20 + idx] =
                    (unsigned int)bf16_rtne(p0) | ((unsigned int)bf16_rtne(p1) << 16);
            }
        // ---- PV(ck) ----
        const short* vc = lds + 16384 + (ck & 1) * 8192;
        __builtin_amdgcn_s_setprio(1);
#pragma unroll
        for (int ct = 0; ct < 16; ct++) {
            bf16x8 v = *(const bf16x8*)&vc[(ct * 16 + idx) * 32 + vsw];
            oacc[0][ct] = __builtin_amdgcn_mfma_f32_16x16x32_bf16(af0, v, oacc[0][ct], 0, 0, 0);
            oacc[1][ct] = __builtin_amdgcn_mfma_f32_16x16x32_bf16(af1, v, oacc[1][ct], 0, 0, 0);
        }
        __builtin_amdgcn_s_setprio(0);
    }
    __syncthreads(); // drain V(nchunk-1)
    {
        bf16x8 af0 = *(const bf16x8*)&psw[idx * 40 + quad * 8];
        bf16x8 af1 = *(const bf16x8*)&psw[640 + idx * 40 + quad * 8];
        const short* vc = lds + 16384 + ((nchunk - 1) & 1) * 8192;
        __builtin_amdgcn_s_setprio(1);
#pragma unroll
        for (int ct = 0; ct < 16; ct++) {
            bf16x8 v = *(const bf16x8*)&vc[(ct * 16 + idx) * 32 + vsw];
            oacc[0][ct] = __builtin_amdgcn_mfma_f32_16x16x32_bf16(af0, v, oacc[0][ct], 0, 0, 0);
            oacc[1][ct] = __builtin_amdgcn_mfma_f32_16x16x32_bf16(af1, v, oacc[1][ct], 0, 0, 0);
        }
        __builtin_amdgcn_s_setprio(0);
    }
    __syncthreads(); // all compute reads of kb/vb done; reuse as epilogue scratch

    // ---- row sums ----
#pragma unroll
    for (int u = 0; u < 2; u++)
#pragma unroll
        for (int r = 0; r < 4; r++) {
            float v = ls[u][r];
            v += __shfl_xor(v, 1);
            v += __shfl_xor(v, 2);
            v += __shfl_xor(v, 4);
            v += __shfl_xor(v, 8);
            if (idx == 0)
                lpart[(size_t)slice * BS_ + b * S_ + q0 + u * 64 + wv * 16 + quad * 4 + r] = v;
        }

    // ---- Opart epilogue: per-wave 16 KB scratch (overlays kb/vb) ----
    short* scr = lds + wv * 8192;
#pragma unroll
    for (int u = 0; u < 2; u++)
#pragma unroll
        for (int ct = 0; ct < 16; ct++) {
            int e = ct * 16 + idx;
#pragma unroll
            for (int r = 0; r < 4; r++) {
                int lr = quad * 4 + r;
                scr[u * 4096 + lr * 256 + ((((e >> 3) ^ (lr & 7)) << 3) | (e & 7))] =
                    (short)bf16_rtne(oacc[u][ct][r]);
            }
        }
#pragma unroll
    for (int u = 0; u < 2; u++) {
        size_t obase = ((size_t)slice * BS_ + (size_t)b * S_ + q0 + u * 64 + wv * 16) * E_;
#pragma unroll
        for (int j = 0; j < 8; j++) {
            int unit = j * 64 + lane; // 512 units of 8 shorts
            *(bf16x8*)(Opart + obase + (size_t)unit * 8) =
                *(const bf16x8*)&scr[u * 4096 + unit * 8];
        }
    }
}

// ---------------------------------------------------------------------------
// proj: out[m][o] = (sum_ns sum_e Opart[ns][m][e]*wo[o][e]) * (1/16)/ltot + bo
// ---------------------------------------------------------------------------
__global__ __launch_bounds__(256) void proj_out(
    const short* __restrict__ Opart, const float* __restrict__ lpart,
    const float* __restrict__ wo, const float* __restrict__ bo,
    float* __restrict__ out) {
    __shared__ __align__(16) short at2[2][16384]; // 64 KB dbuf
    int t = threadIdx.x;
    int m0 = blockIdx.x * 64;
    int lane = t & 63, wv = t >> 6, quad = lane >> 4, idx = lane & 15;

    bf16x8 bw[8];
#pragma unroll
    for (int c = 0; c < 8; c++) {
        const float* ws = wo + idx * E_ + c * 32 + quad * 8;
        f32x4 w0 = *(const f32x4*)ws;
        f32x4 w1 = *(const f32x4*)(ws + 4);
        bw[c] = pack8(w0, w1);
    }

#pragma unroll
    for (int j = 0; j < 8; j++)
        gl_lds16(Opart + (size_t)m0 * E_ + (wv * 8 + j) * 512 + lane * 8,
                 &at2[0][(wv * 8 + j) * 512]);

    f32x4 acc = {0.f, 0.f, 0.f, 0.f};
    for (int ns = 0; ns < NS_; ns++) {
        __syncthreads();
        if (ns + 1 < NS_) {
            const short* src = Opart + ((size_t)(ns + 1) * BS_ + m0) * E_ + lane * 8;
#pragma unroll
            for (int j = 0; j < 8; j++)
                gl_lds16(src + (wv * 8 + j) * 512, &at2[(ns + 1) & 1][(wv * 8 + j) * 512]);
        }
        const short* a = at2[ns & 1];
#pragma unroll
        for (int c = 0; c < 8; c++) {
            bf16x8 af = *(const bf16x8*)&a[(wv * 16 + idx) * 256 +
                                           ((((c * 4 + quad) ^ (idx & 7)) << 3))];
            acc = __builtin_amdgcn_mfma_f32_16x16x32_bf16(af, bw[c], acc, 0, 0, 0);
        }
    }
#pragma unroll
    for (int r = 0; r < 4; r++) {
        int m = m0 + wv * 16 + quad * 4 + r;
        float ltot = 0.f;
#pragma unroll
        for (int ns = 0; ns < NS_; ns++) ltot += lpart[(size_t)ns * BS_ + m];
        out[(size_t)m * NC_ + idx] = acc[r] * (0.0625f / ltot) + bo[idx];
    }
}

extern "C" void kernel_launch(void* const* d_in, const int* in_sizes, int n_in,
                              void* d_out, int out_size, void* d_ws, size_t ws_size,
                              hipStream_t stream) {
    const float* x  = (const float*)d_in[0];
    const float* wq = (const float*)d_in[1];
    const float* bq = (const float*)d_in[2];
    const float* wk = (const float*)d_in[3];
    const float* bk = (const float*)d_in[4];
    const float* wv = (const float*)d_in[5];
    const float* bv = (const float*)d_in[6];
    const float* wo = (const float*)d_in[7];
    const float* bo = (const float*)d_in[8];
    float* out = (float*)d_out;

    const size_t NEL = (size_t)BS_ * E_; // 4,194,304
    // ws: Qb 8MB | Kb 8MB | Vtc 8MB | Opart 32MB | lpart 256KB = 56.25 MB
    short* Qb = (short*)d_ws;
    short* Kb = Qb + NEL;
    short* Vtc = Kb + NEL;
    short* Opart = Vtc + NEL;
    float* lpart = (float*)(Opart + (size_t)NS_ * NEL);
    // xb/wb overlay Opart (Opart is first written by flash_attn, after qkv_gemm
    // has fully consumed xb/wb -> no extra workspace needed).
    short* xb = Opart;        // BS_*E_ shorts = 8 MB
    short* wb = Opart + NEL;  // 3*E_*E_ shorts = 384 KB

    pack_xw<<<(XUNITS_ + WUNITS_) / 256, 256, 0, stream>>>(x, wq, wk, wv, xb, wb);
    qkv_gemm<<<dim3(3, BS_ / 64), 256, 0, stream>>>(xb, wb, bq, bk, bv, Qb, Kb, Vtc);
    flash_attn<<<dim3(S_ / 128, NS_, B_), 256, 0, stream>>>(Qb, Kb, Vtc, Opart, lpart);
    proj_out<<<BS_ / 64, 256, 0, stream>>>(Opart, lpart, wo, bo, out);
}

// Round 2
// 176.708 us; speedup vs baseline: 1.0173x; 1.0173x over previous
//
#include <hip/hip_runtime.h>
#include <hip/hip_bf16.h>

// B=4, S=4096, E=256, NC=16, fp32 in/out. 4 launches:
//  pack_xw:  x (16MB fp32) + wq/wk/wv -> bf16 once (xb/wb live in Opart region,
//            which is dead until flash writes it).
//  qkv_gemm: global_load_lds(16B) staging of pre-packed bf16 (dbuf, ONE barrier
//            per K-step), XOR-swizzled LDS units. 1-D grid + XCD-aware decode:
//            the 3 sel-blocks sharing an xb row-slab land on the same XCD ->
//            xb re-reads become L2 hits.
//  flash:    Q-tile 128 (u=2), 2 blocks/CU, K dbuf + V dbuf + ps sbuf (74 KB),
//            ONE barrier/chunk, one-behind PV, setprio around MFMA clusters.
//            NEW: XCD-aware block decode (bid%8 round-robin, m09/T1): each XCD
//            owns 2 (b,slice) pairs -> its 2 MB K/V working set is L2-resident,
//            killing the 512 MB L3/HBM re-read stream that was the binder
//            (measured: 64 KB/CU/chunk over 6080-cyc chunks = exactly the
//            24.7 GB/s per-CU fabric share).
//  proj:     MFMA output projection + slice merge + normalize (dbuf staging)

#define S_ 4096
#define E_ 256
#define B_ 4
#define NC_ 16
#define BS_ (B_ * S_)
#define NS_ 4

typedef __attribute__((ext_vector_type(8))) short bf16x8;
typedef __attribute__((ext_vector_type(4))) float f32x4;

__device__ __forceinline__ unsigned short bf16_rtne(float f) {
    unsigned int u = __float_as_uint(f);
    return (unsigned short)((u + 0x7FFFu + ((u >> 16) & 1u)) >> 16);
}
__device__ __forceinline__ bf16x8 pack8(f32x4 a, f32x4 b) {
    bf16x8 r;
#pragma unroll
    for (int i = 0; i < 4; i++) r[i] = (short)bf16_rtne(a[i]);
#pragma unroll
    for (int i = 0; i < 4; i++) r[4 + i] = (short)bf16_rtne(b[i]);
    return r;
}
__device__ __forceinline__ void gl_lds16(const void* g, void* lds) {
    __builtin_amdgcn_global_load_lds(
        (const __attribute__((address_space(1))) unsigned int*)g,
        (__attribute__((address_space(3))) unsigned int*)lds, 16, 0, 0);
}
// XOR swizzle on 16B LDS units: involution (mask from bits >=3 flips bits 0-2).
__device__ __forceinline__ int swz_u(int q) { return q ^ ((q >> 3) & 7); }

// ---------------------------------------------------------------------------
// pack_xw: x[BS,E] fp32 -> xb bf16 ; wq/wk/wv [E,E] fp32 -> wb bf16 (3 slabs).
// Grid 2144 x 256: units of 8 floats. Pure streaming, bit-identical rtne.
// ---------------------------------------------------------------------------
#define XUNITS_ (BS_ * E_ / 8)     // 524288
#define WUNITS_ (3 * E_ * E_ / 8)  // 24576
__global__ __launch_bounds__(256) void pack_xw(
    const float* __restrict__ x, const float* __restrict__ wq,
    const float* __restrict__ wk, const float* __restrict__ wv,
    short* __restrict__ xb, short* __restrict__ wb) {
    int u = blockIdx.x * 256 + threadIdx.x;
    const float* src;
    short* dst;
    if (u < XUNITS_) {
        src = x + (size_t)u * 8;
        dst = xb + (size_t)u * 8;
    } else {
        int u2 = u - XUNITS_;  // < WUNITS_ by grid construction
        int sel = u2 >> 13;    // 8192 units per weight matrix
        int off = (u2 & 8191) * 8;
        src = ((sel == 0) ? wq : (sel == 1) ? wk : wv) + off;
        dst = wb + sel * (E_ * E_) + off;
    }
    f32x4 a = *(const f32x4*)src;
    f32x4 b = *(const f32x4*)(src + 4);
    *(bf16x8*)dst = pack8(a, b);
}

// ---------------------------------------------------------------------------
// qkv_gemm. 1-D grid 768. 256 thr = 4 waves; wave: 16 rows x 256 cols.
// XCD decode: xcd = bid&7 owns m0-groups {32*xcd .. 32*xcd+31}; the 3 sels for
// each m0 run on the same XCD (xb slab 32KB shared -> L2 hit on re-reads).
// Staging: global_load_lds 16B of pre-packed bf16, double-buffered, one
// barrier per K-step, XOR-swizzled LDS units (fragment reads 2-way).
// ---------------------------------------------------------------------------
__global__ __launch_bounds__(256) void qkv_gemm(
    const short* __restrict__ xb, const short* __restrict__ wb,
    const float* __restrict__ bq, const float* __restrict__ bk,
    const float* __restrict__ bv, short* __restrict__ Qb,
    short* __restrict__ Kb, short* __restrict__ Vtc) {
    __shared__ __align__(16) short stg[2][10240]; // 2 x 20KB: xt 256u | wt 1024u
    __shared__ __align__(16) short epi[16896];    // 64x264 (Q/K) or 2x8192 (V)

    int t = threadIdx.x;
    // XCD-aware decode (bid%8 round-robin): r in 0..95, sel = r>>5,
    // m0-group = (xcd<<5)|(r&31)  -> same m0's 3 sels co-located per XCD.
    int lin = blockIdx.x;
    int xcd = lin & 7, r8 = lin >> 3;
    int sel = r8 >> 5;
    int m0 = (((xcd << 5) | (r8 & 31))) * 64;
    int lane = t & 63, wid = t >> 6, quad = lane >> 4, idx = lane & 15;

    const short* wsel = wb + sel * (E_ * E_);
    const float* bias = (sel == 0) ? bq : (sel == 1) ? bk : bv;

    // staging sources (swizzled so LDS physical unit q holds logical swz_u(q))
    int ux = swz_u(t);
    const short* xsrc = xb + (size_t)(m0 + (ux >> 2)) * E_ + (ux & 3) * 8;
    const short* wsrc[4];
#pragma unroll
    for (int i = 0; i < 4; i++) {
        int q = i * 256 + t, u = swz_u(q);
        wsrc[i] = wsel + (size_t)(u >> 2) * E_ + (u & 3) * 8;
    }

    // prologue: stage kc=0 into buf 0
    gl_lds16(xsrc, &stg[0][t * 8]);
#pragma unroll
    for (int i = 0; i < 4; i++) gl_lds16(wsrc[i], &stg[0][(256 + i * 256 + t) * 8]);

    f32x4 zf = {0.f, 0.f, 0.f, 0.f};
    f32x4 acc[16];
#pragma unroll
    for (int i = 0; i < 16; i++) acc[i] = zf;

    int fo = (idx * 4 + quad) ^ (idx >> 1); // swizzled fragment unit offset

    for (int it = 0; it < 8; it++) {
        __syncthreads(); // drains DMAs staged one full K-step ago
        if (it < 7) {
            int kc = (it + 1) * 32;
            short* d = stg[(it + 1) & 1];
            gl_lds16(xsrc + kc, &d[t * 8]);
#pragma unroll
            for (int i = 0; i < 4; i++)
                gl_lds16(wsrc[i] + kc, &d[(256 + i * 256 + t) * 8]);
        }
        const short* cb = stg[it & 1];
        bf16x8 af = *(const bf16x8*)&cb[(wid * 64 + fo) * 8];
        const short* cw = &cb[(256 + fo) * 8];
        __builtin_amdgcn_s_setprio(1);
#pragma unroll
        for (int ct = 0; ct < 16; ct++)
            acc[ct] = __builtin_amdgcn_mfma_f32_16x16x32_bf16(
                af, *(const bf16x8*)&cw[ct * 512], acc[ct], 0, 0, 0);
        __builtin_amdgcn_s_setprio(0);
    }

    int qr = quad * 4;
    if (sel == 2) {
        // V: chunk slab, position = key-interleave permutation + 16B swizzle
#pragma unroll
        for (int ct = 0; ct < 16; ct++) {
            int e = ct * 16 + idx;
            float bb = bias[e];
#pragma unroll
            for (int r = 0; r < 4; r++) {
                int mr = wid * 16 + qr + r; // 0..63
                int ckg = mr >> 5, sin = mr & 31;
                int sp = ((sin & 15) << 1) | (sin >> 4); // interleaved position
                int pos = (sp >> 3) ^ ((e >> 1) & 3);
                epi[ckg * 8192 + e * 32 + pos * 8 + (sp & 7)] =
                    (short)bf16_rtne(acc[ct][r] + bb);
            }
        }
        __syncthreads();
        size_t base = ((size_t)((m0 >> 12) * 128 + ((m0 & (S_ - 1)) >> 5))) * 8192;
#pragma unroll
        for (int j = 0; j < 8; j++) {
            int unit = j * 256 + t;
            *(bf16x8*)(Vtc + base + (size_t)unit * 8) = *(const bf16x8*)&epi[unit * 8];
        }
    } else {
        float alpha = (sel == 0) ? 0.0625f : 1.0f;
#pragma unroll
        for (int ct = 0; ct < 16; ct++) {
            int n = ct * 16 + idx;
            float bb = bias[n];
#pragma unroll
            for (int r = 0; r < 4; r++) {
                int row = wid * 16 + qr + r;
                int col = (sel == 1) ? ((((n >> 3) ^ (row & 7)) << 3) | (n & 7)) : n;
                epi[row * 264 + col] = (short)bf16_rtne((acc[ct][r] + bb) * alpha);
            }
        }
        __syncthreads();
        short* out = (sel == 0) ? Qb : Kb;
#pragma unroll
        for (int j = 0; j < 8; j++) {
            int g = j * 256 + t;
            int row = g >> 5, seg = g & 31;
            *(bf16x8*)(out + (size_t)(m0 + row) * E_ + seg * 8) =
                *(const bf16x8*)&epi[row * 264 + seg * 8];
        }
    }
}

// ---------------------------------------------------------------------------
// Flash. 1-D grid 512. 256 thr = 4 waves; wave owns 2 q-subtiles of 16.
// XCD decode: xcd = bid&7 owns (b,slice) pairs {2*xcd, 2*xcd+1}; the 32
// q-blocks sharing a pair's 1 MB K/V stream run on that XCD -> K/V re-reads
// are per-XCD L2 hits (2 MB working set vs 4 MB L2).
// LDS 74 KB: K dbuf 2x16K | V dbuf 2x16K | ps 10K (padded rows, 2-way).
// One barrier per chunk; one-behind PV; setprio around MFMA clusters.
// ---------------------------------------------------------------------------
__global__ __launch_bounds__(256, 2) void flash_attn(
    const short* __restrict__ Qb, const short* __restrict__ Kb,
    const short* __restrict__ Vtc, short* __restrict__ Opart,
    float* __restrict__ lpart) {
    __shared__ __align__(16) short lds[37888]; // 75776 B
    // kb(par) = lds + par*8192 ; vb(par) = lds + 16384 + par*8192 ; ps at 32768

    int t = threadIdx.x;
    // XCD-aware decode (bid%8 round-robin, bijective):
    int lin = blockIdx.x;                       // 0..511
    int xcd = lin & 7, r8 = lin >> 3;           // r8 0..63
    int pair = (xcd << 1) | (r8 >> 5);          // 0..15
    int b = pair >> 2, slice = pair & 3, q0 = (r8 & 31) * 128;
    int key0 = slice * (S_ / NS_);
    const int nchunk = (S_ / NS_) / 32; // 32
    int lane = t & 63, wv = t >> 6, quad = lane >> 4, idx = lane & 15;

    bf16x8 qf[2][8];
#pragma unroll
    for (int u = 0; u < 2; u++) {
        const short* qrow = Qb + (size_t)(b * S_ + q0 + u * 64 + wv * 16 + idx) * E_ + quad * 8;
#pragma unroll
        for (int c = 0; c < 8; c++) qf[u][c] = *(const bf16x8*)(qrow + c * 32);
    }

    f32x4 zf = {0.f, 0.f, 0.f, 0.f};
    f32x4 oacc[2][16];
#pragma unroll
    for (int u = 0; u < 2; u++)
#pragma unroll
        for (int i = 0; i < 16; i++) oacc[u][i] = zf;
    float ls[2][4] = {{0, 0, 0, 0}, {0, 0, 0, 0}};

    const short* kg = Kb + (size_t)(b * S_ + key0) * E_ + lane * 8;
    const short* vg = Vtc + ((size_t)(b * 128 + (key0 >> 5))) * 8192 + lane * 8;
    short* psw = lds + 32768 + wv * 1280; // per-wave 1280 shorts (2u x 16r x 20dw)
    unsigned int* pswu = (unsigned int*)psw;
    int vsw = (quad ^ ((idx >> 1) & 3)) << 3;

    // prologue: stage K(0), V(0), K(1)
#pragma unroll
    for (int j = 0; j < 4; j++) gl_lds16(kg + (wv * 4 + j) * 512, &lds[(wv * 4 + j) * 512]);
#pragma unroll
    for (int j = 0; j < 4; j++) gl_lds16(vg + (wv * 4 + j) * 512, &lds[16384 + (wv * 4 + j) * 512]);
#pragma unroll
    for (int j = 0; j < 4; j++) gl_lds16(kg + 8192 + (wv * 4 + j) * 512, &lds[8192 + (wv * 4 + j) * 512]);
    __syncthreads();

    // QK(0) + exp(0)
    {
        f32x4 s[4] = {zf, zf, zf, zf};
        __builtin_amdgcn_s_setprio(1);
#pragma unroll
        for (int c = 0; c < 8; c++) {
            int p = (((c * 4 + quad) ^ (idx & 7)) << 3);
            bf16x8 k0 = *(const bf16x8*)&lds[idx * 256 + p];
            bf16x8 k1 = *(const bf16x8*)&lds[(16 + idx) * 256 + p];
            s[0] = __builtin_amdgcn_mfma_f32_16x16x32_bf16(qf[0][c], k0, s[0], 0, 0, 0);
            s[1] = __builtin_amdgcn_mfma_f32_16x16x32_bf16(qf[0][c], k1, s[1], 0, 0, 0);
            s[2] = __builtin_amdgcn_mfma_f32_16x16x32_bf16(qf[1][c], k0, s[2], 0, 0, 0);
            s[3] = __builtin_amdgcn_mfma_f32_16x16x32_bf16(qf[1][c], k1, s[3], 0, 0, 0);
        }
        __builtin_amdgcn_s_setprio(0);
#pragma unroll
        for (int u = 0; u < 2; u++)
#pragma unroll
            for (int r = 0; r < 4; r++) {
                float p0 = __expf(s[u * 2][r]);
                float p1 = __expf(s[u * 2 + 1][r]);
                ls[u][r] += p0 + p1;
                pswu[u * 320 + (quad * 4 + r) * 20 + idx] =
                    (unsigned int)bf16_rtne(p0) | ((unsigned int)bf16_rtne(p1) << 16);
            }
    }

    for (int ck = 0; ck < nchunk - 1; ck++) {
        __syncthreads(); // drains K(ck+1), V(ck) DMAs (staged one full chunk ago)
        if (ck + 2 < nchunk) {
            const short* ks = kg + (size_t)(ck + 2) * 8192;
            short* kd = lds + (ck & 1) * 8192;
#pragma unroll
            for (int j = 0; j < 4; j++) gl_lds16(ks + (wv * 4 + j) * 512, &kd[(wv * 4 + j) * 512]);
        }
        {
            const short* vs = vg + (size_t)(ck + 1) * 8192;
            short* vd = lds + 16384 + ((ck + 1) & 1) * 8192;
#pragma unroll
            for (int j = 0; j < 4; j++) gl_lds16(vs + (wv * 4 + j) * 512, &vd[(wv * 4 + j) * 512]);
        }
        // ---- QK(ck+1) ----
        const short* kc = lds + ((ck + 1) & 1) * 8192;
        f32x4 s[4] = {zf, zf, zf, zf};
        __builtin_amdgcn_s_setprio(1);
#pragma unroll
        for (int c = 0; c < 8; c++) {
            int p = (((c * 4 + quad) ^ (idx & 7)) << 3);
            bf16x8 k0 = *(const bf16x8*)&kc[idx * 256 + p];
            bf16x8 k1 = *(const bf16x8*)&kc[(16 + idx) * 256 + p];
            s[0] = __builtin_amdgcn_mfma_f32_16x16x32_bf16(qf[0][c], k0, s[0], 0, 0, 0);
            s[1] = __builtin_amdgcn_mfma_f32_16x16x32_bf16(qf[0][c], k1, s[1], 0, 0, 0);
            s[2] = __builtin_amdgcn_mfma_f32_16x16x32_bf16(qf[1][c], k0, s[2], 0, 0, 0);
            s[3] = __builtin_amdgcn_mfma_f32_16x16x32_bf16(qf[1][c], k1, s[3], 0, 0, 0);
        }
        __builtin_amdgcn_s_setprio(0);
        // ---- af(ck) read (before exp overwrites ps; per-wave DS is in-order)
        bf16x8 af0 = *(const bf16x8*)&psw[idx * 40 + quad * 8];
        bf16x8 af1 = *(const bf16x8*)&psw[640 + idx * 40 + quad * 8];
        // ---- exp(ck+1) -> ps (independent of PV(ck); hides under it) ----
#pragma unroll
        for (int u = 0; u < 2; u++)
#pragma unroll
            for (int r = 0; r < 4; r++) {
                float p0 = __expf(s[u * 2][r]);
                float p1 = __expf(s[u * 2 + 1][r]);
                ls[u][r] += p0 + p1;
                pswu[u * 320 + (quad * 4 + r) * 20 + idx] =
                    (unsigned int)bf16_rtne(p0) | ((unsigned int)bf16_rtne(p1) << 16);
            }
        // ---- PV(ck) ----
        const short* vc = lds + 16384 + (ck & 1) * 8192;
        __builtin_amdgcn_s_setprio(1);
#pragma unroll
        for (int ct = 0; ct < 16; ct++) {
            bf16x8 v = *(const bf16x8*)&vc[(ct * 16 + idx) * 32 + vsw];
            oacc[0][ct] = __builtin_amdgcn_mfma_f32_16x16x32_bf16(af0, v, oacc[0][ct], 0, 0, 0);
            oacc[1][ct] = __builtin_amdgcn_mfma_f32_16x16x32_bf16(af1, v, oacc[1][ct], 0, 0, 0);
        }
        __builtin_amdgcn_s_setprio(0);
    }
    __syncthreads(); // drain V(nchunk-1)
    {
        bf16x8 af0 = *(const bf16x8*)&psw[idx * 40 + quad * 8];
        bf16x8 af1 = *(const bf16x8*)&psw[640 + idx * 40 + quad * 8];
        const short* vc = lds + 16384 + ((nchunk - 1) & 1) * 8192;
        __builtin_amdgcn_s_setprio(1);
#pragma unroll
        for (int ct = 0; ct < 16; ct++) {
            bf16x8 v = *(const bf16x8*)&vc[(ct * 16 + idx) * 32 + vsw];
            oacc[0][ct] = __builtin_amdgcn_mfma_f32_16x16x32_bf16(af0, v, oacc[0][ct], 0, 0, 0);
            oacc[1][ct] = __builtin_amdgcn_mfma_f32_16x16x32_bf16(af1, v, oacc[1][ct], 0, 0, 0);
        }
        __builtin_amdgcn_s_setprio(0);
    }
    __syncthreads(); // all compute reads of kb/vb done; reuse as epilogue scratch

    // ---- row sums ----
#pragma unroll
    for (int u = 0; u < 2; u++)
#pragma unroll
        for (int r = 0; r < 4; r++) {
            float v = ls[u][r];
            v += __shfl_xor(v, 1);
            v += __shfl_xor(v, 2);
            v += __shfl_xor(v, 4);
            v += __shfl_xor(v, 8);
            if (idx == 0)
                lpart[(size_t)slice * BS_ + b * S_ + q0 + u * 64 + wv * 16 + quad * 4 + r] = v;
        }

    // ---- Opart epilogue: per-wave 16 KB scratch (overlays kb/vb) ----
    short* scr = lds + wv * 8192;
#pragma unroll
    for (int u = 0; u < 2; u++)
#pragma unroll
        for (int ct = 0; ct < 16; ct++) {
            int e = ct * 16 + idx;
#pragma unroll
            for (int r = 0; r < 4; r++) {
                int lr = quad * 4 + r;
                scr[u * 4096 + lr * 256 + ((((e >> 3) ^ (lr & 7)) << 3) | (e & 7))] =
                    (short)bf16_rtne(oacc[u][ct][r]);
            }
        }
#pragma unroll
    for (int u = 0; u < 2; u++) {
        size_t obase = ((size_t)slice * BS_ + (size_t)b * S_ + q0 + u * 64 + wv * 16) * E_;
#pragma unroll
        for (int j = 0; j < 8; j++) {
            int unit = j * 64 + lane; // 512 units of 8 shorts
            *(bf16x8*)(Opart + obase + (size_t)unit * 8) =
                *(const bf16x8*)&scr[u * 4096 + unit * 8];
        }
    }
}

// ---------------------------------------------------------------------------
// proj: out[m][o] = (sum_ns sum_e Opart[ns][m][e]*wo[o][e]) * (1/16)/ltot + bo
// ---------------------------------------------------------------------------
__global__ __launch_bounds__(256) void proj_out(
    const short* __restrict__ Opart, const float* __restrict__ lpart,
    const float* __restrict__ wo, const float* __restrict__ bo,
    float* __restrict__ out) {
    __shared__ __align__(16) short at2[2][16384]; // 64 KB dbuf
    int t = threadIdx.x;
    int m0 = blockIdx.x * 64;
    int lane = t & 63, wv = t >> 6, quad = lane >> 4, idx = lane & 15;

    bf16x8 bw[8];
#pragma unroll
    for (int c = 0; c < 8; c++) {
        const float* ws = wo + idx * E_ + c * 32 + quad * 8;
        f32x4 w0 = *(const f32x4*)ws;
        f32x4 w1 = *(const f32x4*)(ws + 4);
        bw[c] = pack8(w0, w1);
    }

#pragma unroll
    for (int j = 0; j < 8; j++)
        gl_lds16(Opart + (size_t)m0 * E_ + (wv * 8 + j) * 512 + lane * 8,
                 &at2[0][(wv * 8 + j) * 512]);

    f32x4 acc = {0.f, 0.f, 0.f, 0.f};
    for (int ns = 0; ns < NS_; ns++) {
        __syncthreads();
        if (ns + 1 < NS_) {
            const short* src = Opart + ((size_t)(ns + 1) * BS_ + m0) * E_ + lane * 8;
#pragma unroll
            for (int j = 0; j < 8; j++)
                gl_lds16(src + (wv * 8 + j) * 512, &at2[(ns + 1) & 1][(wv * 8 + j) * 512]);
        }
        const short* a = at2[ns & 1];
#pragma unroll
        for (int c = 0; c < 8; c++) {
            bf16x8 af = *(const bf16x8*)&a[(wv * 16 + idx) * 256 +
                                           ((((c * 4 + quad) ^ (idx & 7)) << 3))];
            acc = __builtin_amdgcn_mfma_f32_16x16x32_bf16(af, bw[c], acc, 0, 0, 0);
        }
    }
#pragma unroll
    for (int r = 0; r < 4; r++) {
        int m = m0 + wv * 16 + quad * 4 + r;
        float ltot = 0.f;
#pragma unroll
        for (int ns = 0; ns < NS_; ns++) ltot += lpart[(size_t)ns * BS_ + m];
        out[(size_t)m * NC_ + idx] = acc[r] * (0.0625f / ltot) + bo[idx];
    }
}

extern "C" void kernel_launch(void* const* d_in, const int* in_sizes, int n_in,
                              void* d_out, int out_size, void* d_ws, size_t ws_size,
                              hipStream_t stream) {
    const float* x  = (const float*)d_in[0];
    const float* wq = (const float*)d_in[1];
    const float* bq = (const float*)d_in[2];
    const float* wk = (const float*)d_in[3];
    const float* bk = (const float*)d_in[4];
    const float* wv = (const float*)d_in[5];
    const float* bv = (const float*)d_in[6];
    const float* wo = (const float*)d_in[7];
    const float* bo = (const float*)d_in[8];
    float* out = (float*)d_out;

    const size_t NEL = (size_t)BS_ * E_; // 4,194,304
    // ws: Qb 8MB | Kb 8MB | Vtc 8MB | Opart 32MB | lpart 256KB = 56.25 MB
    short* Qb = (short*)d_ws;
    short* Kb = Qb + NEL;
    short* Vtc = Kb + NEL;
    short* Opart = Vtc + NEL;
    float* lpart = (float*)(Opart + (size_t)NS_ * NEL);
    // xb/wb overlay Opart (Opart is first written by flash_attn, after qkv_gemm
    // has fully consumed xb/wb -> no extra workspace needed).
    short* xb = Opart;        // BS_*E_ shorts = 8 MB
    short* wb = Opart + NEL;  // 3*E_*E_ shorts = 384 KB

    pack_xw<<<(XUNITS_ + WUNITS_) / 256, 256, 0, stream>>>(x, wq, wk, wv, xb, wb);
    qkv_gemm<<<dim3(768), 256, 0, stream>>>(xb, wb, bq, bk, bv, Qb, Kb, Vtc);
    flash_attn<<<dim3(512), 256, 0, stream>>>(Qb, Kb, Vtc, Opart, lpart);
    proj_out<<<BS_ / 64, 256, 0, stream>>>(Opart, lpart, wo, bo, out);
}

// Round 3
// 170.281 us; speedup vs baseline: 1.0557x; 1.0377x over previous
//
#include <hip/hip_runtime.h>
#include <hip/hip_bf16.h>

// B=4, S=4096, E=256, NC=16, fp32 in/out. 4 launches:
//  pack_xw:  x + wq/wk/wv + wo -> bf16 once; also zeros the fp32 partial-out
//            accumulator (flash atomically adds into it).
//  qkv_gemm: global_load_lds(16B) staging of pre-packed bf16 (dbuf, ONE barrier
//            per K-step), XOR-swizzled LDS units, XCD-aware decode (R2: made
//            xb re-reads L2 hits).
//  flash:    Q-tile 128 (u=2), 2 blocks/CU, K dbuf + V dbuf + ps sbuf (74 KB),
//            ONE barrier/chunk, one-behind PV, setprio, XCD decode (R2: K/V
//            L2-resident, FETCH 71->17.5MB). NEW: fused output projection —
//            after the O scatter to LDS scr (same transposed layout old proj
//            consumed), multiply by wo (16x256 bf16, L2-hot) and atomicAdd the
//            128x16 fp32 tile into partial. Kills the 32MB Opart write + 32MB
//            proj re-read. af ps-reads hoisted to top of chunk loop.
//  norm_out: out[m][o] = partial[m][o] * (1/16)/ltot[m] + bo[o]  (1MB stream)

#define S_ 4096
#define E_ 256
#define B_ 4
#define NC_ 16
#define BS_ (B_ * S_)
#define NS_ 4

typedef __attribute__((ext_vector_type(8))) short bf16x8;
typedef __attribute__((ext_vector_type(4))) float f32x4;

__device__ __forceinline__ unsigned short bf16_rtne(float f) {
    unsigned int u = __float_as_uint(f);
    return (unsigned short)((u + 0x7FFFu + ((u >> 16) & 1u)) >> 16);
}
__device__ __forceinline__ bf16x8 pack8(f32x4 a, f32x4 b) {
    bf16x8 r;
#pragma unroll
    for (int i = 0; i < 4; i++) r[i] = (short)bf16_rtne(a[i]);
#pragma unroll
    for (int i = 0; i < 4; i++) r[4 + i] = (short)bf16_rtne(b[i]);
    return r;
}
__device__ __forceinline__ void gl_lds16(const void* g, void* lds) {
    __builtin_amdgcn_global_load_lds(
        (const __attribute__((address_space(1))) unsigned int*)g,
        (__attribute__((address_space(3))) unsigned int*)lds, 16, 0, 0);
}
// XOR swizzle on 16B LDS units: involution (mask from bits >=3 flips bits 0-2).
__device__ __forceinline__ int swz_u(int q) { return q ^ ((q >> 3) & 7); }

// ---------------------------------------------------------------------------
// pack_xw: x[BS,E] fp32 -> xb bf16; wq/wk/wv [E,E] -> wb; wo [NC,E] -> wbo;
// zero partial[BS,NC] f32. Grid 2274 x 256, units of 8 elems.
// ---------------------------------------------------------------------------
#define XUNITS_ (BS_ * E_ / 8)      // 524288
#define WUNITS_ (3 * E_ * E_ / 8)   // 24576
#define WOUNITS_ (NC_ * E_ / 8)     // 512
#define ZUNITS_ (BS_ * NC_ / 8)     // 32768
__global__ __launch_bounds__(256) void pack_xw(
    const float* __restrict__ x, const float* __restrict__ wq,
    const float* __restrict__ wk, const float* __restrict__ wv,
    const float* __restrict__ wo, short* __restrict__ xb,
    short* __restrict__ wb, short* __restrict__ wbo,
    float* __restrict__ partial) {
    int u = blockIdx.x * 256 + threadIdx.x;
    const float* src;
    short* dst;
    if (u < XUNITS_) {
        src = x + (size_t)u * 8;
        dst = xb + (size_t)u * 8;
    } else if (u < XUNITS_ + WUNITS_) {
        int u2 = u - XUNITS_;
        int sel = u2 >> 13;  // 8192 units per weight matrix
        int off = (u2 & 8191) * 8;
        src = ((sel == 0) ? wq : (sel == 1) ? wk : wv) + off;
        dst = wb + sel * (E_ * E_) + off;
    } else if (u < XUNITS_ + WUNITS_ + WOUNITS_) {
        int u2 = u - (XUNITS_ + WUNITS_);
        src = wo + (size_t)u2 * 8;
        dst = wbo + (size_t)u2 * 8;
    } else {
        int zu = u - (XUNITS_ + WUNITS_ + WOUNITS_);  // < ZUNITS_
        f32x4 z = {0.f, 0.f, 0.f, 0.f};
        ((f32x4*)partial)[zu * 2] = z;
        ((f32x4*)partial)[zu * 2 + 1] = z;
        return;
    }
    f32x4 a = *(const f32x4*)src;
    f32x4 b = *(const f32x4*)(src + 4);
    *(bf16x8*)dst = pack8(a, b);
}

// ---------------------------------------------------------------------------
// qkv_gemm. 1-D grid 768. 256 thr = 4 waves; wave: 16 rows x 256 cols.
// XCD decode: xcd = bid&7; same m0's 3 sels co-located per XCD (xb L2 hits).
// ---------------------------------------------------------------------------
__global__ __launch_bounds__(256) void qkv_gemm(
    const short* __restrict__ xb, const short* __restrict__ wb,
    const float* __restrict__ bq, const float* __restrict__ bk,
    const float* __restrict__ bv, short* __restrict__ Qb,
    short* __restrict__ Kb, short* __restrict__ Vtc) {
    __shared__ __align__(16) short stg[2][10240]; // 2 x 20KB: xt 256u | wt 1024u
    __shared__ __align__(16) short epi[16896];    // 64x264 (Q/K) or 2x8192 (V)

    int t = threadIdx.x;
    int lin = blockIdx.x;
    int xcd = lin & 7, r8 = lin >> 3;
    int sel = r8 >> 5;
    int m0 = (((xcd << 5) | (r8 & 31))) * 64;
    int lane = t & 63, wid = t >> 6, quad = lane >> 4, idx = lane & 15;

    const short* wsel = wb + sel * (E_ * E_);
    const float* bias = (sel == 0) ? bq : (sel == 1) ? bk : bv;

    int ux = swz_u(t);
    const short* xsrc = xb + (size_t)(m0 + (ux >> 2)) * E_ + (ux & 3) * 8;
    const short* wsrc[4];
#pragma unroll
    for (int i = 0; i < 4; i++) {
        int q = i * 256 + t, u = swz_u(q);
        wsrc[i] = wsel + (size_t)(u >> 2) * E_ + (u & 3) * 8;
    }

    gl_lds16(xsrc, &stg[0][t * 8]);
#pragma unroll
    for (int i = 0; i < 4; i++) gl_lds16(wsrc[i], &stg[0][(256 + i * 256 + t) * 8]);

    f32x4 zf = {0.f, 0.f, 0.f, 0.f};
    f32x4 acc[16];
#pragma unroll
    for (int i = 0; i < 16; i++) acc[i] = zf;

    int fo = (idx * 4 + quad) ^ (idx >> 1); // swizzled fragment unit offset

    for (int it = 0; it < 8; it++) {
        __syncthreads(); // drains DMAs staged one full K-step ago
        if (it < 7) {
            int kc = (it + 1) * 32;
            short* d = stg[(it + 1) & 1];
            gl_lds16(xsrc + kc, &d[t * 8]);
#pragma unroll
            for (int i = 0; i < 4; i++)
                gl_lds16(wsrc[i] + kc, &d[(256 + i * 256 + t) * 8]);
        }
        const short* cb = stg[it & 1];
        bf16x8 af = *(const bf16x8*)&cb[(wid * 64 + fo) * 8];
        const short* cw = &cb[(256 + fo) * 8];
        __builtin_amdgcn_s_setprio(1);
#pragma unroll
        for (int ct = 0; ct < 16; ct++)
            acc[ct] = __builtin_amdgcn_mfma_f32_16x16x32_bf16(
                af, *(const bf16x8*)&cw[ct * 512], acc[ct], 0, 0, 0);
        __builtin_amdgcn_s_setprio(0);
    }

    int qr = quad * 4;
    if (sel == 2) {
#pragma unroll
        for (int ct = 0; ct < 16; ct++) {
            int e = ct * 16 + idx;
            float bb = bias[e];
#pragma unroll
            for (int r = 0; r < 4; r++) {
                int mr = wid * 16 + qr + r; // 0..63
                int ckg = mr >> 5, sin = mr & 31;
                int sp = ((sin & 15) << 1) | (sin >> 4); // interleaved position
                int pos = (sp >> 3) ^ ((e >> 1) & 3);
                epi[ckg * 8192 + e * 32 + pos * 8 + (sp & 7)] =
                    (short)bf16_rtne(acc[ct][r] + bb);
            }
        }
        __syncthreads();
        size_t base = ((size_t)((m0 >> 12) * 128 + ((m0 & (S_ - 1)) >> 5))) * 8192;
#pragma unroll
        for (int j = 0; j < 8; j++) {
            int unit = j * 256 + t;
            *(bf16x8*)(Vtc + base + (size_t)unit * 8) = *(const bf16x8*)&epi[unit * 8];
        }
    } else {
        float alpha = (sel == 0) ? 0.0625f : 1.0f;
#pragma unroll
        for (int ct = 0; ct < 16; ct++) {
            int n = ct * 16 + idx;
            float bb = bias[n];
#pragma unroll
            for (int r = 0; r < 4; r++) {
                int row = wid * 16 + qr + r;
                int col = (sel == 1) ? ((((n >> 3) ^ (row & 7)) << 3) | (n & 7)) : n;
                epi[row * 264 + col] = (short)bf16_rtne((acc[ct][r] + bb) * alpha);
            }
        }
        __syncthreads();
        short* out = (sel == 0) ? Qb : Kb;
#pragma unroll
        for (int j = 0; j < 8; j++) {
            int g = j * 256 + t;
            int row = g >> 5, seg = g & 31;
            *(bf16x8*)(out + (size_t)(m0 + row) * E_ + seg * 8) =
                *(const bf16x8*)&epi[row * 264 + seg * 8];
        }
    }
}

// ---------------------------------------------------------------------------
// Flash + fused out-projection. 1-D grid 512, XCD decode (K/V L2-resident).
// LDS 74 KB: K dbuf 2x16K | V dbuf 2x16K | ps 10K (padded rows, 2-way).
// One barrier per chunk; one-behind PV; setprio around MFMA clusters.
// Epilogue: O scatter to per-wave scr (transposed+swizzled layout), then
// 16 MFMAs vs wo fragments, atomicAdd 128x16 fp32 tile into partial.
// ---------------------------------------------------------------------------
__global__ __launch_bounds__(256, 2) void flash_attn(
    const short* __restrict__ Qb, const short* __restrict__ Kb,
    const short* __restrict__ Vtc, const short* __restrict__ wbo,
    float* __restrict__ partial, float* __restrict__ lpart) {
    __shared__ __align__(16) short lds[37888]; // 75776 B
    // kb(par) = lds + par*8192 ; vb(par) = lds + 16384 + par*8192 ; ps at 32768

    int t = threadIdx.x;
    int lin = blockIdx.x;                       // 0..511
    int xcd = lin & 7, r8 = lin >> 3;           // r8 0..63
    int pair = (xcd << 1) | (r8 >> 5);          // 0..15
    int b = pair >> 2, slice = pair & 3, q0 = (r8 & 31) * 128;
    int key0 = slice * (S_ / NS_);
    const int nchunk = (S_ / NS_) / 32; // 32
    int lane = t & 63, wv = t >> 6, quad = lane >> 4, idx = lane & 15;

    bf16x8 qf[2][8];
#pragma unroll
    for (int u = 0; u < 2; u++) {
        const short* qrow = Qb + (size_t)(b * S_ + q0 + u * 64 + wv * 16 + idx) * E_ + quad * 8;
#pragma unroll
        for (int c = 0; c < 8; c++) qf[u][c] = *(const bf16x8*)(qrow + c * 32);
    }

    f32x4 zf = {0.f, 0.f, 0.f, 0.f};
    f32x4 oacc[2][16];
#pragma unroll
    for (int u = 0; u < 2; u++)
#pragma unroll
        for (int i = 0; i < 16; i++) oacc[u][i] = zf;
    float ls[2][4] = {{0, 0, 0, 0}, {0, 0, 0, 0}};

    const short* kg = Kb + (size_t)(b * S_ + key0) * E_ + lane * 8;
    const short* vg = Vtc + ((size_t)(b * 128 + (key0 >> 5))) * 8192 + lane * 8;
    short* psw = lds + 32768 + wv * 1280; // per-wave 1280 shorts (2u x 16r x 20dw)
    unsigned int* pswu = (unsigned int*)psw;
    int vsw = (quad ^ ((idx >> 1) & 3)) << 3;

    // prologue: stage K(0), V(0), K(1)
#pragma unroll
    for (int j = 0; j < 4; j++) gl_lds16(kg + (wv * 4 + j) * 512, &lds[(wv * 4 + j) * 512]);
#pragma unroll
    for (int j = 0; j < 4; j++) gl_lds16(vg + (wv * 4 + j) * 512, &lds[16384 + (wv * 4 + j) * 512]);
#pragma unroll
    for (int j = 0; j < 4; j++) gl_lds16(kg + 8192 + (wv * 4 + j) * 512, &lds[8192 + (wv * 4 + j) * 512]);
    __syncthreads();

    // QK(0) + exp(0)
    {
        f32x4 s[4] = {zf, zf, zf, zf};
        __builtin_amdgcn_s_setprio(1);
#pragma unroll
        for (int c = 0; c < 8; c++) {
            int p = (((c * 4 + quad) ^ (idx & 7)) << 3);
            bf16x8 k0 = *(const bf16x8*)&lds[idx * 256 + p];
            bf16x8 k1 = *(const bf16x8*)&lds[(16 + idx) * 256 + p];
            s[0] = __builtin_amdgcn_mfma_f32_16x16x32_bf16(qf[0][c], k0, s[0], 0, 0, 0);
            s[1] = __builtin_amdgcn_mfma_f32_16x16x32_bf16(qf[0][c], k1, s[1], 0, 0, 0);
            s[2] = __builtin_amdgcn_mfma_f32_16x16x32_bf16(qf[1][c], k0, s[2], 0, 0, 0);
            s[3] = __builtin_amdgcn_mfma_f32_16x16x32_bf16(qf[1][c], k1, s[3], 0, 0, 0);
        }
        __builtin_amdgcn_s_setprio(0);
#pragma unroll
        for (int u = 0; u < 2; u++)
#pragma unroll
            for (int r = 0; r < 4; r++) {
                float p0 = __expf(s[u * 2][r]);
                float p1 = __expf(s[u * 2 + 1][r]);
                ls[u][r] += p0 + p1;
                pswu[u * 320 + (quad * 4 + r) * 20 + idx] =
                    (unsigned int)bf16_rtne(p0) | ((unsigned int)bf16_rtne(p1) << 16);
            }
    }

    for (int ck = 0; ck < nchunk - 1; ck++) {
        __syncthreads(); // drains K(ck+1), V(ck) DMAs (staged one full chunk ago)
        // ---- af(ck) read hoisted: full chunk of ds flight before PV needs it.
        // Safe: same-wave DS is in-order; exp(ck+1) writes ps only later.
        bf16x8 af0 = *(const bf16x8*)&psw[idx * 40 + quad * 8];
        bf16x8 af1 = *(const bf16x8*)&psw[640 + idx * 40 + quad * 8];
        if (ck + 2 < nchunk) {
            const short* ks = kg + (size_t)(ck + 2) * 8192;
            short* kd = lds + (ck & 1) * 8192;
#pragma unroll
            for (int j = 0; j < 4; j++) gl_lds16(ks + (wv * 4 + j) * 512, &kd[(wv * 4 + j) * 512]);
        }
        {
            const short* vs = vg + (size_t)(ck + 1) * 8192;
            short* vd = lds + 16384 + ((ck + 1) & 1) * 8192;
#pragma unroll
            for (int j = 0; j < 4; j++) gl_lds16(vs + (wv * 4 + j) * 512, &vd[(wv * 4 + j) * 512]);
        }
        // ---- QK(ck+1) ----
        const short* kc = lds + ((ck + 1) & 1) * 8192;
        f32x4 s[4] = {zf, zf, zf, zf};
        __builtin_amdgcn_s_setprio(1);
#pragma unroll
        for (int c = 0; c < 8; c++) {
            int p = (((c * 4 + quad) ^ (idx & 7)) << 3);
            bf16x8 k0 = *(const bf16x8*)&kc[idx * 256 + p];
            bf16x8 k1 = *(const bf16x8*)&kc[(16 + idx) * 256 + p];
            s[0] = __builtin_amdgcn_mfma_f32_16x16x32_bf16(qf[0][c], k0, s[0], 0, 0, 0);
            s[1] = __builtin_amdgcn_mfma_f32_16x16x32_bf16(qf[0][c], k1, s[1], 0, 0, 0);
            s[2] = __builtin_amdgcn_mfma_f32_16x16x32_bf16(qf[1][c], k0, s[2], 0, 0, 0);
            s[3] = __builtin_amdgcn_mfma_f32_16x16x32_bf16(qf[1][c], k1, s[3], 0, 0, 0);
        }
        __builtin_amdgcn_s_setprio(0);
        // ---- exp(ck+1) -> ps (independent of PV(ck); hides under it) ----
#pragma unroll
        for (int u = 0; u < 2; u++)
#pragma unroll
            for (int r = 0; r < 4; r++) {
                float p0 = __expf(s[u * 2][r]);
                float p1 = __expf(s[u * 2 + 1][r]);
                ls[u][r] += p0 + p1;
                pswu[u * 320 + (quad * 4 + r) * 20 + idx] =
                    (unsigned int)bf16_rtne(p0) | ((unsigned int)bf16_rtne(p1) << 16);
            }
        // ---- PV(ck) ----
        const short* vc = lds + 16384 + (ck & 1) * 8192;
        __builtin_amdgcn_s_setprio(1);
#pragma unroll
        for (int ct = 0; ct < 16; ct++) {
            bf16x8 v = *(const bf16x8*)&vc[(ct * 16 + idx) * 32 + vsw];
            oacc[0][ct] = __builtin_amdgcn_mfma_f32_16x16x32_bf16(af0, v, oacc[0][ct], 0, 0, 0);
            oacc[1][ct] = __builtin_amdgcn_mfma_f32_16x16x32_bf16(af1, v, oacc[1][ct], 0, 0, 0);
        }
        __builtin_amdgcn_s_setprio(0);
    }
    __syncthreads(); // drain V(nchunk-1)
    {
        bf16x8 af0 = *(const bf16x8*)&psw[idx * 40 + quad * 8];
        bf16x8 af1 = *(const bf16x8*)&psw[640 + idx * 40 + quad * 8];
        const short* vc = lds + 16384 + ((nchunk - 1) & 1) * 8192;
        __builtin_amdgcn_s_setprio(1);
#pragma unroll
        for (int ct = 0; ct < 16; ct++) {
            bf16x8 v = *(const bf16x8*)&vc[(ct * 16 + idx) * 32 + vsw];
            oacc[0][ct] = __builtin_amdgcn_mfma_f32_16x16x32_bf16(af0, v, oacc[0][ct], 0, 0, 0);
            oacc[1][ct] = __builtin_amdgcn_mfma_f32_16x16x32_bf16(af1, v, oacc[1][ct], 0, 0, 0);
        }
        __builtin_amdgcn_s_setprio(0);
    }
    __syncthreads(); // all compute reads of kb/vb done; reuse as epilogue scratch

    // ---- row sums ----
#pragma unroll
    for (int u = 0; u < 2; u++)
#pragma unroll
        for (int r = 0; r < 4; r++) {
            float v = ls[u][r];
            v += __shfl_xor(v, 1);
            v += __shfl_xor(v, 2);
            v += __shfl_xor(v, 4);
            v += __shfl_xor(v, 8);
            if (idx == 0)
                lpart[(size_t)slice * BS_ + b * S_ + q0 + u * 64 + wv * 16 + quad * 4 + r] = v;
        }

    // ---- O scatter: per-wave 16 KB scratch (overlays kb/vb), transposed+swz
    short* scr = lds + wv * 8192;
#pragma unroll
    for (int u = 0; u < 2; u++)
#pragma unroll
        for (int ct = 0; ct < 16; ct++) {
            int e = ct * 16 + idx;
#pragma unroll
            for (int r = 0; r < 4; r++) {
                int lr = quad * 4 + r;
                scr[u * 4096 + lr * 256 + ((((e >> 3) ^ (lr & 7)) << 3) | (e & 7))] =
                    (short)bf16_rtne(oacc[u][ct][r]);
            }
        }
    // (no barrier needed: scr is per-wave, DS in-order)

    // ---- fused out-projection: 32q x 256E (bf16) x woT -> 32q x 16o fp32 ----
    f32x4 pacc[2] = {zf, zf};
#pragma unroll
    for (int c = 0; c < 8; c++) {
        bf16x8 bw = *(const bf16x8*)(wbo + idx * E_ + c * 32 + quad * 8);
#pragma unroll
        for (int u = 0; u < 2; u++) {
            bf16x8 af = *(const bf16x8*)&scr[u * 4096 + idx * 256 +
                                             (((c * 4 + quad) ^ (idx & 7)) << 3)];
            pacc[u] = __builtin_amdgcn_mfma_f32_16x16x32_bf16(af, bw, pacc[u], 0, 0, 0);
        }
    }
#pragma unroll
    for (int u = 0; u < 2; u++)
#pragma unroll
        for (int r = 0; r < 4; r++) {
            int m = q0 + u * 64 + wv * 16 + quad * 4 + r;
            atomicAdd(&partial[((size_t)b * S_ + m) * NC_ + idx], pacc[u][r]);
        }
}

// ---------------------------------------------------------------------------
// norm_out: out[m][o] = partial[m][o] * (1/16)/ltot[m] + bo[o]. Grid 1024x256.
// ---------------------------------------------------------------------------
__global__ __launch_bounds__(256) void norm_out(
    const float* __restrict__ partial, const float* __restrict__ lpart,
    const float* __restrict__ bo, float* __restrict__ out) {
    int t = threadIdx.x;
    int m = blockIdx.x * 16 + (t >> 4), o = t & 15;
    float ltot = 0.f;
#pragma unroll
    for (int ns = 0; ns < NS_; ns++) ltot += lpart[(size_t)ns * BS_ + m];
    size_t i = (size_t)m * NC_ + o;
    out[i] = partial[i] * (0.0625f / ltot) + bo[o];
}

extern "C" void kernel_launch(void* const* d_in, const int* in_sizes, int n_in,
                              void* d_out, int out_size, void* d_ws, size_t ws_size,
                              hipStream_t stream) {
    const float* x  = (const float*)d_in[0];
    const float* wq = (const float*)d_in[1];
    const float* bq = (const float*)d_in[2];
    const float* wk = (const float*)d_in[3];
    const float* bk = (const float*)d_in[4];
    const float* wv = (const float*)d_in[5];
    const float* bv = (const float*)d_in[6];
    const float* wo = (const float*)d_in[7];
    const float* bo = (const float*)d_in[8];
    float* out = (float*)d_out;

    const size_t NEL = (size_t)BS_ * E_; // 4,194,304
    // ws (shorts): Qb | Kb | Vtc | xb | wb(3*E*E) | wbo(NC*E) | partial f32 | lpart f32
    short* Qb = (short*)d_ws;
    short* Kb = Qb + NEL;
    short* Vtc = Kb + NEL;
    short* xb = Vtc + NEL;
    short* wb = xb + NEL;
    short* wbo = wb + (size_t)3 * E_ * E_;
    float* partial = (float*)(wbo + (size_t)NC_ * E_);   // BS_*NC_ f32 = 1 MB
    float* lpart = partial + (size_t)BS_ * NC_;          // NS_*BS_ f32 = 256 KB

    pack_xw<<<(XUNITS_ + WUNITS_ + WOUNITS_ + ZUNITS_) / 256, 256, 0, stream>>>(
        x, wq, wk, wv, wo, xb, wb, wbo, partial);
    qkv_gemm<<<dim3(768), 256, 0, stream>>>(xb, wb, bq, bk, bv, Qb, Kb, Vtc);
    flash_attn<<<dim3(512), 256, 0, stream>>>(Qb, Kb, Vtc, wbo, partial, lpart);
    norm_out<<<dim3(BS_ / 16), 256, 0, stream>>>(partial, lpart, bo, out);
}

// Round 4
// 169.884 us; speedup vs baseline: 1.0582x; 1.0023x over previous
//
#include <hip/hip_runtime.h>
#include <hip/hip_bf16.h>

// B=4, S=4096, E=256, NC=16, fp32 in/out. 4 launches:
//  pack_w:   wq/wk/wv + wo -> bf16 once; zeros the fp32 partial accumulator.
//            (x no longer packed: qkv reads fp32 x directly into registers.)
//  qkv_gemm: A-fragments (x rows) loaded fp32->reg->bf16 in prologue (no x LDS,
//            no x pre-pack); K-loop stages ONLY w via global_load_lds 16B
//            (dbuf, ONE barrier/step, XOR-swizzled units, fully unrolled so
//            af[] stays in VGPRs). LDS 65 KB -> 2 blocks/CU. Epilogues and
//            XCD-aware decode unchanged from R3.
//  flash:    UNCHANGED from R3 (byte-identical): Q-tile 128, 2 blocks/CU,
//            K/V dbuf + padded ps, one barrier/chunk, one-behind PV, setprio,
//            XCD decode (K/V L2-resident), fused wo-projection epilogue with
//            atomicAdd into partial.
//  norm_out: out[m][o] = partial[m][o] * (1/16)/ltot[m] + bo[o]  (1MB stream)

#define S_ 4096
#define E_ 256
#define B_ 4
#define NC_ 16
#define BS_ (B_ * S_)
#define NS_ 4

typedef __attribute__((ext_vector_type(8))) short bf16x8;
typedef __attribute__((ext_vector_type(4))) float f32x4;

__device__ __forceinline__ unsigned short bf16_rtne(float f) {
    unsigned int u = __float_as_uint(f);
    return (unsigned short)((u + 0x7FFFu + ((u >> 16) & 1u)) >> 16);
}
__device__ __forceinline__ bf16x8 pack8(f32x4 a, f32x4 b) {
    bf16x8 r;
#pragma unroll
    for (int i = 0; i < 4; i++) r[i] = (short)bf16_rtne(a[i]);
#pragma unroll
    for (int i = 0; i < 4; i++) r[4 + i] = (short)bf16_rtne(b[i]);
    return r;
}
__device__ __forceinline__ void gl_lds16(const void* g, void* lds) {
    __builtin_amdgcn_global_load_lds(
        (const __attribute__((address_space(1))) unsigned int*)g,
        (__attribute__((address_space(3))) unsigned int*)lds, 16, 0, 0);
}
// XOR swizzle on 16B LDS units: involution (mask from bits >=3 flips bits 0-2).
__device__ __forceinline__ int swz_u(int q) { return q ^ ((q >> 3) & 7); }

// ---------------------------------------------------------------------------
// pack_w: wq/wk/wv [E,E] fp32 -> wb bf16 (3 slabs); wo [NC,E] -> wbo;
// zero partial[BS,NC] f32. Grid 226 x 256, units of 8 elems.
// ---------------------------------------------------------------------------
#define WUNITS_ (3 * E_ * E_ / 8)   // 24576
#define WOUNITS_ (NC_ * E_ / 8)     // 512
#define ZUNITS_ (BS_ * NC_ / 8)     // 32768
__global__ __launch_bounds__(256) void pack_w(
    const float* __restrict__ wq, const float* __restrict__ wk,
    const float* __restrict__ wv, const float* __restrict__ wo,
    short* __restrict__ wb, short* __restrict__ wbo,
    float* __restrict__ partial) {
    int u = blockIdx.x * 256 + threadIdx.x;
    const float* src;
    short* dst;
    if (u < WUNITS_) {
        int sel = u >> 13;  // 8192 units per weight matrix
        int off = (u & 8191) * 8;
        src = ((sel == 0) ? wq : (sel == 1) ? wk : wv) + off;
        dst = wb + sel * (E_ * E_) + off;
    } else if (u < WUNITS_ + WOUNITS_) {
        int u2 = u - WUNITS_;
        src = wo + (size_t)u2 * 8;
        dst = wbo + (size_t)u2 * 8;
    } else {
        int zu = u - (WUNITS_ + WOUNITS_);  // < ZUNITS_
        f32x4 z = {0.f, 0.f, 0.f, 0.f};
        ((f32x4*)partial)[zu * 2] = z;
        ((f32x4*)partial)[zu * 2 + 1] = z;
        return;
    }
    f32x4 a = *(const f32x4*)src;
    f32x4 b = *(const f32x4*)(src + 4);
    *(bf16x8*)dst = pack8(a, b);
}

// ---------------------------------------------------------------------------
// qkv_gemm. 1-D grid 768. 256 thr = 4 waves; wave: 16 rows x 256 cols.
// XCD decode: xcd = bid&7; same m0's 3 sels co-located per XCD (x L2 hits).
// A: fp32 x rows -> registers (8 bf16x8/thread) in prologue, bit-identical
// rtne pack. B: w staged via DMA dbuf, one barrier per K-step, swizzled.
// ---------------------------------------------------------------------------
__global__ __launch_bounds__(256) void qkv_gemm(
    const float* __restrict__ x, const short* __restrict__ wb,
    const float* __restrict__ bq, const float* __restrict__ bk,
    const float* __restrict__ bv, short* __restrict__ Qb,
    short* __restrict__ Kb, short* __restrict__ Vtc) {
    __shared__ __align__(16) short stg[2][8192]; // 2 x 16KB: wt 1024 units
    __shared__ __align__(16) short epi[16896];   // 64x264 (Q/K) or 2x8192 (V)

    int t = threadIdx.x;
    int lin = blockIdx.x;
    int xcd = lin & 7, r8 = lin >> 3;
    int sel = r8 >> 5;
    int m0 = (((xcd << 5) | (r8 & 31))) * 64;
    int lane = t & 63, wid = t >> 6, quad = lane >> 4, idx = lane & 15;

    const short* wsel = wb + sel * (E_ * E_);
    const float* bias = (sel == 0) ? bq : (sel == 1) ? bk : bv;

    const short* wsrc[4];
#pragma unroll
    for (int i = 0; i < 4; i++) {
        int q = i * 256 + t, u = swz_u(q);
        wsrc[i] = wsel + (size_t)(u >> 2) * E_ + (u & 3) * 8;
    }

    // prologue: stage w kc=0 into buf 0 (DMA latency hides under x pack)
#pragma unroll
    for (int i = 0; i < 4; i++) gl_lds16(wsrc[i], &stg[0][(i * 256 + t) * 8]);

    // x rows -> registers: row m0+wid*16+idx, cols quad*8 + it*32 .. +7
    const float* xrow = x + (size_t)(m0 + wid * 16 + idx) * E_ + quad * 8;
    bf16x8 af[8];
#pragma unroll
    for (int it = 0; it < 8; it++) {
        f32x4 a0 = *(const f32x4*)(xrow + it * 32);
        f32x4 a1 = *(const f32x4*)(xrow + it * 32 + 4);
        af[it] = pack8(a0, a1);
    }

    f32x4 zf = {0.f, 0.f, 0.f, 0.f};
    f32x4 acc[16];
#pragma unroll
    for (int i = 0; i < 16; i++) acc[i] = zf;

    int fo = (idx * 4 + quad) ^ (idx >> 1); // swizzled fragment unit offset

#pragma unroll
    for (int it = 0; it < 8; it++) {
        __syncthreads(); // drains DMAs staged one full K-step ago
        if (it < 7) {
            int kc = (it + 1) * 32;
            short* d = stg[(it + 1) & 1];
#pragma unroll
            for (int i = 0; i < 4; i++)
                gl_lds16(wsrc[i] + kc, &d[(i * 256 + t) * 8]);
        }
        const short* cw = &stg[it & 1][fo * 8];
        __builtin_amdgcn_s_setprio(1);
#pragma unroll
        for (int ct = 0; ct < 16; ct++)
            acc[ct] = __builtin_amdgcn_mfma_f32_16x16x32_bf16(
                af[it], *(const bf16x8*)&cw[ct * 512], acc[ct], 0, 0, 0);
        __builtin_amdgcn_s_setprio(0);
    }

    int qr = quad * 4;
    if (sel == 2) {
        // V: chunk slab, position = key-interleave permutation + 16B swizzle
#pragma unroll
        for (int ct = 0; ct < 16; ct++) {
            int e = ct * 16 + idx;
            float bb = bias[e];
#pragma unroll
            for (int r = 0; r < 4; r++) {
                int mr = wid * 16 + qr + r; // 0..63
                int ckg = mr >> 5, sin = mr & 31;
                int sp = ((sin & 15) << 1) | (sin >> 4); // interleaved position
                int pos = (sp >> 3) ^ ((e >> 1) & 3);
                epi[ckg * 8192 + e * 32 + pos * 8 + (sp & 7)] =
                    (short)bf16_rtne(acc[ct][r] + bb);
            }
        }
        __syncthreads();
        size_t base = ((size_t)((m0 >> 12) * 128 + ((m0 & (S_ - 1)) >> 5))) * 8192;
#pragma unroll
        for (int j = 0; j < 8; j++) {
            int unit = j * 256 + t;
            *(bf16x8*)(Vtc + base + (size_t)unit * 8) = *(const bf16x8*)&epi[unit * 8];
        }
    } else {
        float alpha = (sel == 0) ? 0.0625f : 1.0f;
#pragma unroll
        for (int ct = 0; ct < 16; ct++) {
            int n = ct * 16 + idx;
            float bb = bias[n];
#pragma unroll
            for (int r = 0; r < 4; r++) {
                int row = wid * 16 + qr + r;
                int col = (sel == 1) ? ((((n >> 3) ^ (row & 7)) << 3) | (n & 7)) : n;
                epi[row * 264 + col] = (short)bf16_rtne((acc[ct][r] + bb) * alpha);
            }
        }
        __syncthreads();
        short* out = (sel == 0) ? Qb : Kb;
#pragma unroll
        for (int j = 0; j < 8; j++) {
            int g = j * 256 + t;
            int row = g >> 5, seg = g & 31;
            *(bf16x8*)(out + (size_t)(m0 + row) * E_ + seg * 8) =
                *(const bf16x8*)&epi[row * 264 + seg * 8];
        }
    }
}

// ---------------------------------------------------------------------------
// Flash + fused out-projection. UNCHANGED from R3. 1-D grid 512, XCD decode.
// ---------------------------------------------------------------------------
__global__ __launch_bounds__(256, 2) void flash_attn(
    const short* __restrict__ Qb, const short* __restrict__ Kb,
    const short* __restrict__ Vtc, const short* __restrict__ wbo,
    float* __restrict__ partial, float* __restrict__ lpart) {
    __shared__ __align__(16) short lds[37888]; // 75776 B
    // kb(par) = lds + par*8192 ; vb(par) = lds + 16384 + par*8192 ; ps at 32768

    int t = threadIdx.x;
    int lin = blockIdx.x;                       // 0..511
    int xcd = lin & 7, r8 = lin >> 3;           // r8 0..63
    int pair = (xcd << 1) | (r8 >> 5);          // 0..15
    int b = pair >> 2, slice = pair & 3, q0 = (r8 & 31) * 128;
    int key0 = slice * (S_ / NS_);
    const int nchunk = (S_ / NS_) / 32; // 32
    int lane = t & 63, wv = t >> 6, quad = lane >> 4, idx = lane & 15;

    bf16x8 qf[2][8];
#pragma unroll
    for (int u = 0; u < 2; u++) {
        const short* qrow = Qb + (size_t)(b * S_ + q0 + u * 64 + wv * 16 + idx) * E_ + quad * 8;
#pragma unroll
        for (int c = 0; c < 8; c++) qf[u][c] = *(const bf16x8*)(qrow + c * 32);
    }

    f32x4 zf = {0.f, 0.f, 0.f, 0.f};
    f32x4 oacc[2][16];
#pragma unroll
    for (int u = 0; u < 2; u++)
#pragma unroll
        for (int i = 0; i < 16; i++) oacc[u][i] = zf;
    float ls[2][4] = {{0, 0, 0, 0}, {0, 0, 0, 0}};

    const short* kg = Kb + (size_t)(b * S_ + key0) * E_ + lane * 8;
    const short* vg = Vtc + ((size_t)(b * 128 + (key0 >> 5))) * 8192 + lane * 8;
    short* psw = lds + 32768 + wv * 1280; // per-wave 1280 shorts (2u x 16r x 20dw)
    unsigned int* pswu = (unsigned int*)psw;
    int vsw = (quad ^ ((idx >> 1) & 3)) << 3;

    // prologue: stage K(0), V(0), K(1)
#pragma unroll
    for (int j = 0; j < 4; j++) gl_lds16(kg + (wv * 4 + j) * 512, &lds[(wv * 4 + j) * 512]);
#pragma unroll
    for (int j = 0; j < 4; j++) gl_lds16(vg + (wv * 4 + j) * 512, &lds[16384 + (wv * 4 + j) * 512]);
#pragma unroll
    for (int j = 0; j < 4; j++) gl_lds16(kg + 8192 + (wv * 4 + j) * 512, &lds[8192 + (wv * 4 + j) * 512]);
    __syncthreads();

    // QK(0) + exp(0)
    {
        f32x4 s[4] = {zf, zf, zf, zf};
        __builtin_amdgcn_s_setprio(1);
#pragma unroll
        for (int c = 0; c < 8; c++) {
            int p = (((c * 4 + quad) ^ (idx & 7)) << 3);
            bf16x8 k0 = *(const bf16x8*)&lds[idx * 256 + p];
            bf16x8 k1 = *(const bf16x8*)&lds[(16 + idx) * 256 + p];
            s[0] = __builtin_amdgcn_mfma_f32_16x16x32_bf16(qf[0][c], k0, s[0], 0, 0, 0);
            s[1] = __builtin_amdgcn_mfma_f32_16x16x32_bf16(qf[0][c], k1, s[1], 0, 0, 0);
            s[2] = __builtin_amdgcn_mfma_f32_16x16x32_bf16(qf[1][c], k0, s[2], 0, 0, 0);
            s[3] = __builtin_amdgcn_mfma_f32_16x16x32_bf16(qf[1][c], k1, s[3], 0, 0, 0);
        }
        __builtin_amdgcn_s_setprio(0);
#pragma unroll
        for (int u = 0; u < 2; u++)
#pragma unroll
            for (int r = 0; r < 4; r++) {
                float p0 = __expf(s[u * 2][r]);
                float p1 = __expf(s[u * 2 + 1][r]);
                ls[u][r] += p0 + p1;
                pswu[u * 320 + (quad * 4 + r) * 20 + idx] =
                    (unsigned int)bf16_rtne(p0) | ((unsigned int)bf16_rtne(p1) << 16);
            }
    }

    for (int ck = 0; ck < nchunk - 1; ck++) {
        __syncthreads(); // drains K(ck+1), V(ck) DMAs (staged one full chunk ago)
        // ---- af(ck) read hoisted: full chunk of ds flight before PV needs it.
        bf16x8 af0 = *(const bf16x8*)&psw[idx * 40 + quad * 8];
        bf16x8 af1 = *(const bf16x8*)&psw[640 + idx * 40 + quad * 8];
        if (ck + 2 < nchunk) {
            const short* ks = kg + (size_t)(ck + 2) * 8192;
            short* kd = lds + (ck & 1) * 8192;
#pragma unroll
            for (int j = 0; j < 4; j++) gl_lds16(ks + (wv * 4 + j) * 512, &kd[(wv * 4 + j) * 512]);
        }
        {
            const short* vs = vg + (size_t)(ck + 1) * 8192;
            short* vd = lds + 16384 + ((ck + 1) & 1) * 8192;
#pragma unroll
            for (int j = 0; j < 4; j++) gl_lds16(vs + (wv * 4 + j) * 512, &vd[(wv * 4 + j) * 512]);
        }
        // ---- QK(ck+1) ----
        const short* kc = lds + ((ck + 1) & 1) * 8192;
        f32x4 s[4] = {zf, zf, zf, zf};
        __builtin_amdgcn_s_setprio(1);
#pragma unroll
        for (int c = 0; c < 8; c++) {
            int p = (((c * 4 + quad) ^ (idx & 7)) << 3);
            bf16x8 k0 = *(const bf16x8*)&kc[idx * 256 + p];
            bf16x8 k1 = *(const bf16x8*)&kc[(16 + idx) * 256 + p];
            s[0] = __builtin_amdgcn_mfma_f32_16x16x32_bf16(qf[0][c], k0, s[0], 0, 0, 0);
            s[1] = __builtin_amdgcn_mfma_f32_16x16x32_bf16(qf[0][c], k1, s[1], 0, 0, 0);
            s[2] = __builtin_amdgcn_mfma_f32_16x16x32_bf16(qf[1][c], k0, s[2], 0, 0, 0);
            s[3] = __builtin_amdgcn_mfma_f32_16x16x32_bf16(qf[1][c], k1, s[3], 0, 0, 0);
        }
        __builtin_amdgcn_s_setprio(0);
        // ---- exp(ck+1) -> ps (independent of PV(ck); hides under it) ----
#pragma unroll
        for (int u = 0; u < 2; u++)
#pragma unroll
            for (int r = 0; r < 4; r++) {
                float p0 = __expf(s[u * 2][r]);
                float p1 = __expf(s[u * 2 + 1][r]);
                ls[u][r] += p0 + p1;
                pswu[u * 320 + (quad * 4 + r) * 20 + idx] =
                    (unsigned int)bf16_rtne(p0) | ((unsigned int)bf16_rtne(p1) << 16);
            }
        // ---- PV(ck) ----
        const short* vc = lds + 16384 + (ck & 1) * 8192;
        __builtin_amdgcn_s_setprio(1);
#pragma unroll
        for (int ct = 0; ct < 16; ct++) {
            bf16x8 v = *(const bf16x8*)&vc[(ct * 16 + idx) * 32 + vsw];
            oacc[0][ct] = __builtin_amdgcn_mfma_f32_16x16x32_bf16(af0, v, oacc[0][ct], 0, 0, 0);
            oacc[1][ct] = __builtin_amdgcn_mfma_f32_16x16x32_bf16(af1, v, oacc[1][ct], 0, 0, 0);
        }
        __builtin_amdgcn_s_setprio(0);
    }
    __syncthreads(); // drain V(nchunk-1)
    {
        bf16x8 af0 = *(const bf16x8*)&psw[idx * 40 + quad * 8];
        bf16x8 af1 = *(const bf16x8*)&psw[640 + idx * 40 + quad * 8];
        const short* vc = lds + 16384 + ((nchunk - 1) & 1) * 8192;
        __builtin_amdgcn_s_setprio(1);
#pragma unroll
        for (int ct = 0; ct < 16; ct++) {
            bf16x8 v = *(const bf16x8*)&vc[(ct * 16 + idx) * 32 + vsw];
            oacc[0][ct] = __builtin_amdgcn_mfma_f32_16x16x32_bf16(af0, v, oacc[0][ct], 0, 0, 0);
            oacc[1][ct] = __builtin_amdgcn_mfma_f32_16x16x32_bf16(af1, v, oacc[1][ct], 0, 0, 0);
        }
        __builtin_amdgcn_s_setprio(0);
    }
    __syncthreads(); // all compute reads of kb/vb done; reuse as epilogue scratch

    // ---- row sums ----
#pragma unroll
    for (int u = 0; u < 2; u++)
#pragma unroll
        for (int r = 0; r < 4; r++) {
            float v = ls[u][r];
            v += __shfl_xor(v, 1);
            v += __shfl_xor(v, 2);
            v += __shfl_xor(v, 4);
            v += __shfl_xor(v, 8);
            if (idx == 0)
                lpart[(size_t)slice * BS_ + b * S_ + q0 + u * 64 + wv * 16 + quad * 4 + r] = v;
        }

    // ---- O scatter: per-wave 16 KB scratch (overlays kb/vb), transposed+swz
    short* scr = lds + wv * 8192;
#pragma unroll
    for (int u = 0; u < 2; u++)
#pragma unroll
        for (int ct = 0; ct < 16; ct++) {
            int e = ct * 16 + idx;
#pragma unroll
            for (int r = 0; r < 4; r++) {
                int lr = quad * 4 + r;
                scr[u * 4096 + lr * 256 + ((((e >> 3) ^ (lr & 7)) << 3) | (e & 7))] =
                    (short)bf16_rtne(oacc[u][ct][r]);
            }
        }
    // (no barrier needed: scr is per-wave, DS in-order)

    // ---- fused out-projection: 32q x 256E (bf16) x woT -> 32q x 16o fp32 ----
    f32x4 pacc[2] = {zf, zf};
#pragma unroll
    for (int c = 0; c < 8; c++) {
        bf16x8 bw = *(const bf16x8*)(wbo + idx * E_ + c * 32 + quad * 8);
#pragma unroll
        for (int u = 0; u < 2; u++) {
            bf16x8 af = *(const bf16x8*)&scr[u * 4096 + idx * 256 +
                                             (((c * 4 + quad) ^ (idx & 7)) << 3)];
            pacc[u] = __builtin_amdgcn_mfma_f32_16x16x32_bf16(af, bw, pacc[u], 0, 0, 0);
        }
    }
#pragma unroll
    for (int u = 0; u < 2; u++)
#pragma unroll
        for (int r = 0; r < 4; r++) {
            int m = q0 + u * 64 + wv * 16 + quad * 4 + r;
            atomicAdd(&partial[((size_t)b * S_ + m) * NC_ + idx], pacc[u][r]);
        }
}

// ---------------------------------------------------------------------------
// norm_out: out[m][o] = partial[m][o] * (1/16)/ltot[m] + bo[o]. Grid 1024x256.
// ---------------------------------------------------------------------------
__global__ __launch_bounds__(256) void norm_out(
    const float* __restrict__ partial, const float* __restrict__ lpart,
    const float* __restrict__ bo, float* __restrict__ out) {
    int t = threadIdx.x;
    int m = blockIdx.x * 16 + (t >> 4), o = t & 15;
    float ltot = 0.f;
#pragma unroll
    for (int ns = 0; ns < NS_; ns++) ltot += lpart[(size_t)ns * BS_ + m];
    size_t i = (size_t)m * NC_ + o;
    out[i] = partial[i] * (0.0625f / ltot) + bo[o];
}

extern "C" void kernel_launch(void* const* d_in, const int* in_sizes, int n_in,
                              void* d_out, int out_size, void* d_ws, size_t ws_size,
                              hipStream_t stream) {
    const float* x  = (const float*)d_in[0];
    const float* wq = (const float*)d_in[1];
    const float* bq = (const float*)d_in[2];
    const float* wk = (const float*)d_in[3];
    const float* bk = (const float*)d_in[4];
    const float* wv = (const float*)d_in[5];
    const float* bv = (const float*)d_in[6];
    const float* wo = (const float*)d_in[7];
    const float* bo = (const float*)d_in[8];
    float* out = (float*)d_out;

    const size_t NEL = (size_t)BS_ * E_; // 4,194,304
    // ws (shorts): Qb | Kb | Vtc | wb(3*E*E) | wbo(NC*E) | partial f32 | lpart f32
    short* Qb = (short*)d_ws;
    short* Kb = Qb + NEL;
    short* Vtc = Kb + NEL;
    short* wb = Vtc + NEL;
    short* wbo = wb + (size_t)3 * E_ * E_;
    float* partial = (float*)(wbo + (size_t)NC_ * E_);   // BS_*NC_ f32 = 1 MB
    float* lpart = partial + (size_t)BS_ * NC_;          // NS_*BS_ f32 = 256 KB

    pack_w<<<(WUNITS_ + WOUNITS_ + ZUNITS_) / 256, 256, 0, stream>>>(
        wq, wk, wv, wo, wb, wbo, partial);
    qkv_gemm<<<dim3(768), 256, 0, stream>>>(x, wb, bq, bk, bv, Qb, Kb, Vtc);
    flash_attn<<<dim3(512), 256, 0, stream>>>(Qb, Kb, Vtc, wbo, partial, lpart);
    norm_out<<<dim3(BS_ / 16), 256, 0, stream>>>(partial, lpart, bo, out);
}